// Round 7
// baseline (537.006 us; speedup 1.0000x reference)
//
#include <hip/hip_runtime.h>
#include <math.h>

// Problem constants: H=300, D=600, B=256 graphs, Nu=Nv=8192, batch SORTED.
#define HDIM 300
#define DDIM 600
#define NGR  256

typedef float vf4 __attribute__((ext_vector_type(4)));
typedef float vf2 __attribute__((ext_vector_type(2)));

__device__ __forceinline__ float wred_sum(float v){
  #pragma unroll
  for(int o=32;o;o>>=1) v += __shfl_xor(v,o,64);
  return v;
}
__device__ __forceinline__ float wred_max(float v){
  #pragma unroll
  for(int o=32;o;o>>=1) v = fmaxf(v,__shfl_xor(v,o,64));
  return v;
}
__device__ __forceinline__ float sigm(float x){ return 1.f/(1.f+expf(-x)); }

// Zero-fill map row i outside its in-graph span [js,je) (NT float4 stores).
// Depends only on ub/voff; disjoint from dot writes -> can ride in any kernel
// that runs after K1.
__device__ __forceinline__ void fill_row(int i, const int* __restrict__ ub,
    const int* __restrict__ voff, float* __restrict__ mapbase, int Nv, int tid){
  int g = ub[i];
  int js = voff[g], je = voff[g+1];
  float* mrow = mapbase + (size_t)i*Nv;
  const vf4 z4 = {0.f,0.f,0.f,0.f};
  int nf4 = Nv >> 2;
  for (int q4=tid; q4<nf4; q4+=256){
    int j0 = q4*4;
    if (j0+4 <= js || j0 >= je){
      __builtin_nontemporal_store(z4, (vf4*)(mrow + j0));
    } else {
      #pragma unroll
      for(int u=0;u<4;u++){ int j=j0+u; if (j<js || j>=je) mrow[j]=0.f; }
    }
  }
}

// Bresenham compute/fill split: grid G = C compute + F fill, uniformly
// interleaved in dispatch order. Returns compute index or -1 (then fi set).
__device__ __forceinline__ int split_cf(int b, int C, int G, int* fi){
  unsigned ci = (unsigned)(((unsigned long long)b * (unsigned)C) / (unsigned)G);
  unsigned cn = (unsigned)(((unsigned long long)(b+1) * (unsigned)C) / (unsigned)G);
  if (cn == ci){ *fi = b - (int)ci; return -1; }
  return (int)ci;
}

// ---- K1: blocks [0,NBn): l2-normalize rows (4 waves/block);
//  NBn: offsets (binary search) + step-1 LSTM closed form + out init;
//  (NBn, NBn+600]: gbase (recomputes bias-only h1 locally -> no cross-block dep).
__global__ __launch_bounds__(256) void k_norm_off(const float* __restrict__ xu,
    const float* __restrict__ xv, float* __restrict__ su, float* __restrict__ sv,
    int Nu, int Nv, const int* __restrict__ ub, const int* __restrict__ vb,
    int* __restrict__ uoff, int* __restrict__ voff,
    const float* __restrict__ b_ih, const float* __restrict__ b_hh,
    float* __restrict__ h1, float* __restrict__ c1,
    const float* __restrict__ pb, float* __restrict__ outp,
    const float* __restrict__ Wih, const float* __restrict__ Whh,
    float* __restrict__ gbase){
  int NBn = (Nu + Nv) >> 2;
  int b = blockIdx.x;
  int tid = threadIdx.x, lane = tid & 63, w = tid >> 6;
  if (b == NBn){
    int t = tid;
    if (t < NGR){
      int lo=0, hi=Nu;
      while(lo<hi){ int m=(lo+hi)>>1; if (ub[m] < t) lo=m+1; else hi=m; }
      uoff[t]=lo;
      lo=0; hi=Nv;
      while(lo<hi){ int m=(lo+hi)>>1; if (vb[m] < t) lo=m+1; else hi=m; }
      voff[t]=lo;
      if (t==0){ uoff[NGR]=Nu; voff[NGR]=Nv; }
      outp[t] = pb[0];
    }
    for (int d=tid; d<DDIM; d+=256){
      float gi = b_ih[d]      + b_hh[d];
      float gg = b_ih[1200+d] + b_hh[1200+d];
      float go = b_ih[1800+d] + b_hh[1800+d];
      float c  = sigm(gi)*tanhf(gg);       // f*c0 = 0
      c1[d]=c; h1[d]=sigm(go)*tanhf(c);
    }
    return;
  }
  if (b > NBn){                            // gbase blocks
    __shared__ float h1l[DDIM];
    for (int d=tid; d<DDIM; d+=256){       // recompute bias-only h1 locally
      float gi = b_ih[d]      + b_hh[d];
      float gg = b_ih[1200+d] + b_hh[1200+d];
      float go = b_ih[1800+d] + b_hh[1800+d];
      float c  = sigm(gi)*tanhf(gg);
      h1l[d]   = sigm(go)*tanhf(c);
    }
    __syncthreads();
    int n = (b - NBn - 1)*4 + w;           // 600 blocks x 4 waves = 2400 rows
    const float* wi = Wih + (size_t)n*1200;
    const float* wh = Whh + (size_t)n*600;
    float s = 0.f;
    for (int k=lane; k<DDIM; k+=64) s += h1l[k]*(wi[k] + wh[k]);
    s = wred_sum(s);
    if (lane==0) gbase[n] = s + b_ih[n] + b_hh[n];
    return;
  }
  int wid = b*4 + w;
  const float* src; float* dst;
  if (wid < Nu){ src = xu + (size_t)wid*HDIM; dst = su + (size_t)wid*HDIM; }
  else         { src = xv + (size_t)(wid-Nu)*HDIM; dst = sv + (size_t)(wid-Nu)*HDIM; }
  const vf4* s4 = (const vf4*)src;
  vf4 A = s4[lane];
  vf4 Bv = (lane<11)? s4[64+lane] : (vf4){0.f,0.f,0.f,0.f};
  float s = A.x*A.x+A.y*A.y+A.z*A.z+A.w*A.w + Bv.x*Bv.x+Bv.y*Bv.y+Bv.z*Bv.z+Bv.w*Bv.w;
  s = wred_sum(s);
  float inv = 1.f / fmaxf(sqrtf(s), 1e-12f);
  vf4* d4 = (vf4*)dst;
  d4[lane] = A*inv;
  if (lane<11) d4[64+lane] = Bv*inv;
}

// ---- K2: grid 21845 = 16384 compute + 5461 fill (rows [0,5461)),
// Bresenham-interleaved so store-bound fill rides under compute on every CU.
__global__ __launch_bounds__(256) void k_prime(const float* __restrict__ su,
    const float* __restrict__ sv, const int* __restrict__ ub,
    const int* __restrict__ vb, const int* __restrict__ uoff,
    const int* __restrict__ voff, float* __restrict__ spr,
    float* __restrict__ svp, float* __restrict__ e1u, float* __restrict__ e1v,
    const float* __restrict__ h1, float* __restrict__ mapbase, int Nu, int Nv){
  int tid = threadIdx.x, lane = tid & 63, w = tid >> 6;
  int fi;
  int idx = split_cf(blockIdx.x, 16384, 21845, &fi);
  if (idx < 0){ fill_row(fi, ub, voff, mapbase, Nv, tid); return; }
  bool isU = (idx < Nu);
  int i = isU ? idx : idx - Nu;
  const float* xa = isU ? su : sv;
  const float* xb = isU ? sv : su;
  const int* mybatch = isU ? ub : vb;
  const int* ooff    = isU ? voff : uoff;
  float* prime = isU ? spr : svp;
  float* eout  = isU ? e1u : e1v;

  __shared__ __align__(16) float xrow[304];
  __shared__ __align__(16) float prl[4*304];
  __shared__ float qv[2*HDIM];
  __shared__ float red[4];
  const float* rowp = xa + (size_t)i*HDIM;
  for (int t=tid; t<HDIM;   t+=256) xrow[t] = rowp[t];
  for (int t=tid; t<2*HDIM; t+=256) qv[t]   = h1[t];
  int g = mybatch[i];
  int js = ooff[g], je = ooff[g+1];
  __syncthreads();

  const vf4* x4 = (const vf4*)xrow;
  vf4 xA = x4[lane];
  vf4 xB = (lane<11)? x4[64+lane] : (vf4){0.f,0.f,0.f,0.f};
  vf4 prA = {0.f,0.f,0.f,0.f}, prB = {0.f,0.f,0.f,0.f};
  for (int j = js + w; j < je; j += 4){
    const vf4* orow = (const vf4*)(xb + (size_t)j*HDIM);
    vf4 oA = orow[lane];
    vf4 oB = (lane<11)? orow[64+lane] : (vf4){0.f,0.f,0.f,0.f};
    float d = oA.x*xA.x + oA.y*xA.y + oA.z*xA.z + oA.w*xA.w
            + oB.x*xB.x + oB.y*xB.y + oB.z*xB.z + oB.w*xB.w;
    d = wred_sum(d);
    if (isU && lane==0) mapbase[(size_t)i*Nv + j] = d;
    prA += d * oA;
    prB += d * oB;
  }
  vf4* p4 = (vf4*)(prl + w*304);
  p4[lane] = prA;
  if (lane<11) p4[64+lane] = prB;
  __syncthreads();
  float ep = 0.f;
  for (int t=tid; t<HDIM; t+=256){
    float s = prl[t] + prl[304+t] + prl[608+t] + prl[912+t];
    prime[(size_t)i*HDIM + t] = s;
    ep += xrow[t]*qv[t] + s*qv[HDIM+t];
  }
  ep = wred_sum(ep);
  if (lane==0) red[w] = ep;
  __syncthreads();
  if (tid==0) eout[i] = red[0]+red[1]+red[2]+red[3];
}

// ---- K3: grid 1877 = 512 softmax/r1 compute + 1365 fill (rows [5461,6826))
__global__ __launch_bounds__(256) void k_r1(const float* __restrict__ su,
    const float* __restrict__ sv, const float* __restrict__ spr,
    const float* __restrict__ svp, const float* __restrict__ e1u,
    const float* __restrict__ e1v, const int* __restrict__ uoff,
    const int* __restrict__ voff, float* __restrict__ r1,
    const int* __restrict__ ub, float* __restrict__ mapbase, int Nv){
  int tid = threadIdx.x, lane = tid & 63, w = tid >> 6;
  int fi;
  int bs = split_cf(blockIdx.x, 512, 1877, &fi);
  if (bs < 0){ fill_row(5461 + fi, ub, voff, mapbase, Nv, tid); return; }
  int set = bs >> 8; int g = bs & 255;
  const float* x  = set? sv  : su;
  const float* pr = set? svp : spr;
  const float* e  = set? e1v : e1u;
  const int* off  = set? voff: uoff;
  __shared__ float al[2048]; __shared__ float red[4]; __shared__ float shv;
  int ns = off[g], ne = off[g+1]; int n = ne - ns;
  float m = -INFINITY;
  for (int t=ns+tid; t<ne; t+=256) m = fmaxf(m, e[t]);
  m = wred_max(m);
  if (lane==0) red[w]=m;
  __syncthreads();
  if (tid==0) shv = fmaxf(fmaxf(red[0],red[1]),fmaxf(red[2],red[3]));
  __syncthreads();
  float emax = shv;
  float s = 0.f;
  for (int t=tid; t<n; t+=256){ float a = expf(e[ns+t]-emax); if (t<2048) al[t]=a; s += a; }
  s = wred_sum(s);
  __syncthreads();
  if (lane==0) red[w]=s;
  __syncthreads();
  if (tid==0) shv = red[0]+red[1]+red[2]+red[3];
  __syncthreads();
  float inv = 1.f/(shv + 1e-16f);
  float acc[3] = {0.f,0.f,0.f};
  for (int nn=0; nn<n; nn++){
    float a = (nn<2048)? al[nn] : expf(e[ns+nn]-emax);
    const float* xr = x  + (size_t)(ns+nn)*HDIM;
    const float* pp = pr + (size_t)(ns+nn)*HDIM;
    #pragma unroll
    for(int u=0;u<3;u++){ int c = tid + u*256; if (c<DDIM){
        float xv = (c<HDIM)? xr[c] : pp[c-HDIM]; acc[u] += a*xv; } }
  }
  #pragma unroll
  for(int u=0;u<3;u++){ int c = tid + u*256; if (c<DDIM) r1[(size_t)bs*DDIM + c] = acc[u]*inv; }
}

// ---- K4: fused GEMM (gates = r1 @ Wih[:,600:].T) + step-2 LSTM pointwise.
// 32 gs x 64 col tile (cols = 4 gates x 16 d), grid 38x16 = 608 blocks. -----
__global__ __launch_bounds__(256) void k_gemm_lstm(const float* __restrict__ r1,
    const float* __restrict__ Wih, const float* __restrict__ gbase,
    const float* __restrict__ c1, float* __restrict__ h2){
  __shared__ __align__(16) float smem[32*68];   // gates phase; K phase aliases
  float* Al = smem;            // 16*36
  float* Bl = smem + 16*36;    // 16*68
  int tid = threadIdx.x;
  int d0  = blockIdx.x*16;     // 38 blocks: d0 = 0..592 (last has 8 valid)
  int gs0 = blockIdx.y*32;
  int tx = tid & 15, ty = tid >> 4;
  float acc[2][4] = {};
  for (int kt=0; kt<600; kt+=16){
    int k = kt + tx;
    bool kok = (k < 600);
    #pragma unroll
    for (int u=0; u<2; u++){
      int rl = ty + u*16;
      Al[tx*36 + rl] = kok ? r1[(size_t)(gs0+rl)*DDIM + k] : 0.f;
    }
    #pragma unroll
    for (int u=0; u<4; u++){
      int cl = ty + u*16;                 // 0..63
      int gate = cl >> 4, dd = cl & 15;
      int d = d0 + dd;
      Bl[tx*68 + cl] = (kok && d < 600)
          ? Wih[(size_t)(gate*600 + d)*1200 + 600 + k] : 0.f;
    }
    __syncthreads();
    #pragma unroll
    for (int kk=0; kk<16; kk++){
      vf2 av = ((const vf2*)(Al + kk*36))[ty];
      vf4 bv = ((const vf4*)(Bl + kk*68))[tx];
      float a[2]={av.x,av.y}, bb[4]={bv.x,bv.y,bv.z,bv.w};
      #pragma unroll
      for(int mm=0;mm<2;mm++)
        #pragma unroll
        for(int nn=0;nn<4;nn++) acc[mm][nn] += a[mm]*bb[nn];
    }
    __syncthreads();
  }
  #pragma unroll
  for (int mm=0; mm<2; mm++){
    vf4 o = {acc[mm][0], acc[mm][1], acc[mm][2], acc[mm][3]};
    ((vf4*)(smem + (ty*2+mm)*68))[tx] = o;
  }
  __syncthreads();
  int d_l = tid & 15, r0 = tid >> 4;
  int d = d0 + d_l;
  if (d < 600){
    float gb_i = gbase[d], gb_f = gbase[600+d], gb_g = gbase[1200+d], gb_o = gbase[1800+d];
    float cc1 = c1[d];
    #pragma unroll
    for (int u=0; u<2; u++){
      int rl = r0 + u*16;
      const float* gr = smem + rl*68;
      float gi = gr[d_l]      + gb_i;
      float gf = gr[16+d_l]   + gb_f;
      float gG = gr[32+d_l]   + gb_g;
      float go = gr[48+d_l]   + gb_o;
      float c  = sigm(gf)*cc1 + sigm(gi)*tanhf(gG);
      h2[(size_t)(gs0+rl)*DDIM + d] = sigm(go)*tanhf(c);
    }
  }
}

// ---- K5: grid 1878 = 512 e2/softmax/r2/pred compute + 1366 fill
// (rows [6826,8192)). -------------------------------------------------------
__global__ __launch_bounds__(256) void k_r2(const float* __restrict__ su,
    const float* __restrict__ sv, const float* __restrict__ spr,
    const float* __restrict__ svp, const int* __restrict__ uoff,
    const int* __restrict__ voff, const float* __restrict__ h2,
    const float* __restrict__ pW, float* __restrict__ e2u,
    float* __restrict__ e2v, float* __restrict__ outp,
    const int* __restrict__ ub, float* __restrict__ mapbase, int Nv){
  int tid = threadIdx.x, lane = tid & 63, w = tid >> 6;
  int fi;
  int bs = split_cf(blockIdx.x, 512, 1878, &fi);
  if (bs < 0){ fill_row(6826 + fi, ub, voff, mapbase, Nv, tid); return; }
  int set = bs >> 8; int g = bs & 255;
  const float* x  = set? sv  : su;
  const float* pr = set? svp : spr;
  const int* off  = set? voff: uoff;
  float* e2g      = set? e2v : e2u;        // overflow fallback only
  __shared__ float q[DDIM]; __shared__ float e2l[128]; __shared__ float al[128];
  __shared__ float red[4]; __shared__ float shv;
  for (int t=tid; t<DDIM; t+=256) q[t] = h2[(size_t)bs*DDIM + t];
  int ns = off[g], ne = off[g+1]; int n = ne - ns;
  __syncthreads();
  for (int node = ns + w; node < ne; node += 4){
    const float* xr = x  + (size_t)node*HDIM;
    const float* pp = pr + (size_t)node*HDIM;
    float d = 0.f;
    #pragma unroll
    for(int c=0;c<10;c++){ int k = lane + 64*c; if (k<DDIM){
        float xv = (k<HDIM)? xr[k] : pp[k-HDIM]; d += xv*q[k]; } }
    d = wred_sum(d);
    if (lane==0){ int t = node-ns; if (t<128) e2l[t] = d; else e2g[node] = d; }
  }
  __syncthreads();
  float m = -INFINITY;
  for (int t=tid; t<n; t+=256) m = fmaxf(m, (t<128)? e2l[t] : e2g[ns+t]);
  m = wred_max(m);
  if (lane==0) red[w]=m;
  __syncthreads();
  if (tid==0) shv = fmaxf(fmaxf(red[0],red[1]),fmaxf(red[2],red[3]));
  __syncthreads();
  float emax = shv;
  float s = 0.f;
  for (int t=tid; t<n; t+=256){
    float a = expf(((t<128)? e2l[t] : e2g[ns+t]) - emax);
    if (t<128) al[t]=a; else e2g[ns+t]=a;
    s += a;
  }
  s = wred_sum(s);
  __syncthreads();
  if (lane==0) red[w]=s;
  __syncthreads();
  if (tid==0) shv = red[0]+red[1]+red[2]+red[3];
  __syncthreads();
  float inv = 1.f/(shv + 1e-16f);
  float acc[3] = {0.f,0.f,0.f};
  for (int nn=0; nn<n; nn++){
    float a = (nn<128)? al[nn] : e2g[ns+nn];
    const float* xr = x  + (size_t)(ns+nn)*HDIM;
    const float* pp = pr + (size_t)(ns+nn)*HDIM;
    #pragma unroll
    for(int u=0;u<3;u++){ int c = tid + u*256; if (c<DDIM){
        float xv = (c<HDIM)? xr[c] : pp[c-HDIM]; acc[u] += a*xv; } }
  }
  int hoff = set? 1200 : 0;
  float p = 0.f;
  #pragma unroll
  for(int u=0;u<3;u++){ int c = tid + u*256; if (c<DDIM) p += (acc[u]*inv)*pW[hoff+600+c]; }
  for (int t=tid; t<DDIM; t+=256) p += q[t]*pW[hoff+t];
  p = wred_sum(p);
  __syncthreads();
  if (lane==0) red[w] = p;
  __syncthreads();
  if (tid==0) atomicAdd(&outp[g], red[0]+red[1]+red[2]+red[3]);
}

extern "C" void kernel_launch(void* const* d_in, const int* in_sizes, int n_in,
                              void* d_out, int out_size, void* d_ws, size_t ws_size,
                              hipStream_t stream) {
  const float* solute_x  = (const float*)d_in[0];
  const float* solvent_x = (const float*)d_in[1];
  const int*   ub        = (const int*)d_in[2];
  const int*   vb        = (const int*)d_in[3];
  const float* Wih  = (const float*)d_in[5];
  const float* Whh  = (const float*)d_in[6];
  const float* b_ih = (const float*)d_in[7];
  const float* b_hh = (const float*)d_in[8];
  const float* pW   = (const float*)d_in[9];
  const float* pb   = (const float*)d_in[10];

  int Nu = in_sizes[0] / HDIM;
  int Nv = in_sizes[1] / HDIM;

  float* out = (float*)d_out;
  int predn = out_size - Nu*Nv;        // = 256
  float* mapbase = out + predn;

  float* ws = (float*)d_ws;
  float* su    = ws;
  float* sv    = su    + (size_t)Nu*HDIM;
  float* spr   = sv    + (size_t)Nv*HDIM;
  float* svp   = spr   + (size_t)Nu*HDIM;
  float* e1u   = svp   + (size_t)Nv*HDIM;  // Nu
  float* e1v   = e1u   + Nu;               // Nv
  float* h1    = e1v   + Nv;               // 600
  float* c1    = h1    + DDIM;             // 600
  float* r1    = c1    + DDIM;             // 512*600
  float* gbase = r1    + 512*DDIM;         // 2400
  float* h2    = gbase + 2400;             // 512*600
  int*   uoff  = (int*)(h2 + 512*DDIM);    // 257
  int*   voff  = uoff + 257;               // 257

  // Fill split (Bresenham-interleaved): K2 rows [0,5461), K3 [5461,6826),
  // K5 [6826,8192).
  k_norm_off<<<dim3((Nu+Nv)/4 + 1 + 600), dim3(256), 0, stream>>>(
      solute_x, solvent_x, su, sv, Nu, Nv, ub, vb, uoff, voff,
      b_ih, b_hh, h1, c1, pb, out, Wih, Whh, gbase);
  k_prime<<<dim3(21845), dim3(256), 0, stream>>>(
      su, sv, ub, vb, uoff, voff, spr, svp, e1u, e1v, h1, mapbase, Nu, Nv);
  k_r1<<<dim3(1877), dim3(256), 0, stream>>>(
      su, sv, spr, svp, e1u, e1v, uoff, voff, r1, ub, mapbase, Nv);
  k_gemm_lstm<<<dim3(38, 16), dim3(256), 0, stream>>>(r1, Wih, gbase, c1, h2);
  k_r2<<<dim3(1878), dim3(256), 0, stream>>>(
      su, sv, spr, svp, uoff, voff, h2, pW, e1u, e1v, out, ub, mapbase, Nv);
}

// Round 8
// 518.165 us; speedup vs baseline: 1.0364x; 1.0364x over previous
//
#include <hip/hip_runtime.h>
#include <math.h>

// Problem constants: H=300, D=600, B=256 graphs, Nu=Nv=8192, batch SORTED.
#define HDIM 300
#define DDIM 600
#define NGR  256

typedef float vf4 __attribute__((ext_vector_type(4)));
typedef float vf2 __attribute__((ext_vector_type(2)));

__device__ __forceinline__ float wred_sum(float v){
  #pragma unroll
  for(int o=32;o;o>>=1) v += __shfl_xor(v,o,64);
  return v;
}
__device__ __forceinline__ float wred_max(float v){
  #pragma unroll
  for(int o=32;o;o>>=1) v = fmaxf(v,__shfl_xor(v,o,64));
  return v;
}
__device__ __forceinline__ float sigm(float x){ return 1.f/(1.f+expf(-x)); }

// Zero-fill map row i outside its in-graph span [js,je) (NT float4 stores).
__device__ __forceinline__ void fill_row(int i, const int* __restrict__ ub,
    const int* __restrict__ voff, float* __restrict__ mapbase, int Nv, int tid){
  int g = ub[i];
  int js = voff[g], je = voff[g+1];
  float* mrow = mapbase + (size_t)i*Nv;
  const vf4 z4 = {0.f,0.f,0.f,0.f};
  int nf4 = Nv >> 2;
  for (int q4=tid; q4<nf4; q4+=256){
    int j0 = q4*4;
    if (j0+4 <= js || j0 >= je){
      __builtin_nontemporal_store(z4, (vf4*)(mrow + j0));
    } else {
      #pragma unroll
      for(int u=0;u<4;u++){ int j=j0+u; if (j<js || j>=je) mrow[j]=0.f; }
    }
  }
}

// ---- K1: blocks [0,NBn): l2-normalize rows (4 waves/block);
//  NBn: offsets (binary search) + step-1 LSTM closed form + out init;
//  (NBn, NBn+600]: gbase (recomputes bias-only h1 locally -> no cross-block dep).
__global__ __launch_bounds__(256) void k_norm_off(const float* __restrict__ xu,
    const float* __restrict__ xv, float* __restrict__ su, float* __restrict__ sv,
    int Nu, int Nv, const int* __restrict__ ub, const int* __restrict__ vb,
    int* __restrict__ uoff, int* __restrict__ voff,
    const float* __restrict__ b_ih, const float* __restrict__ b_hh,
    float* __restrict__ h1, float* __restrict__ c1,
    const float* __restrict__ pb, float* __restrict__ outp,
    const float* __restrict__ Wih, const float* __restrict__ Whh,
    float* __restrict__ gbase){
  int NBn = (Nu + Nv) >> 2;
  int b = blockIdx.x;
  int tid = threadIdx.x, lane = tid & 63, w = tid >> 6;
  if (b == NBn){
    int t = tid;
    if (t < NGR){
      int lo=0, hi=Nu;
      while(lo<hi){ int m=(lo+hi)>>1; if (ub[m] < t) lo=m+1; else hi=m; }
      uoff[t]=lo;
      lo=0; hi=Nv;
      while(lo<hi){ int m=(lo+hi)>>1; if (vb[m] < t) lo=m+1; else hi=m; }
      voff[t]=lo;
      if (t==0){ uoff[NGR]=Nu; voff[NGR]=Nv; }
      outp[t] = pb[0];
    }
    for (int d=tid; d<DDIM; d+=256){
      float gi = b_ih[d]      + b_hh[d];
      float gg = b_ih[1200+d] + b_hh[1200+d];
      float go = b_ih[1800+d] + b_hh[1800+d];
      float c  = sigm(gi)*tanhf(gg);       // f*c0 = 0
      c1[d]=c; h1[d]=sigm(go)*tanhf(c);
    }
    return;
  }
  if (b > NBn){                            // gbase blocks
    __shared__ float h1l[DDIM];
    for (int d=tid; d<DDIM; d+=256){       // recompute bias-only h1 locally
      float gi = b_ih[d]      + b_hh[d];
      float gg = b_ih[1200+d] + b_hh[1200+d];
      float go = b_ih[1800+d] + b_hh[1800+d];
      float c  = sigm(gi)*tanhf(gg);
      h1l[d]   = sigm(go)*tanhf(c);
    }
    __syncthreads();
    int n = (b - NBn - 1)*4 + w;           // 600 blocks x 4 waves = 2400 rows
    const float* wi = Wih + (size_t)n*1200;
    const float* wh = Whh + (size_t)n*600;
    float s = 0.f;
    for (int k=lane; k<DDIM; k+=64) s += h1l[k]*(wi[k] + wh[k]);
    s = wred_sum(s);
    if (lane==0) gbase[n] = s + b_ih[n] + b_hh[n];
    return;
  }
  int wid = b*4 + w;
  const float* src; float* dst;
  if (wid < Nu){ src = xu + (size_t)wid*HDIM; dst = su + (size_t)wid*HDIM; }
  else         { src = xv + (size_t)(wid-Nu)*HDIM; dst = sv + (size_t)(wid-Nu)*HDIM; }
  const vf4* s4 = (const vf4*)src;
  vf4 A = s4[lane];
  vf4 Bv = (lane<11)? s4[64+lane] : (vf4){0.f,0.f,0.f,0.f};
  float s = A.x*A.x+A.y*A.y+A.z*A.z+A.w*A.w + Bv.x*Bv.x+Bv.y*Bv.y+Bv.z*Bv.z+Bv.w*Bv.w;
  s = wred_sum(s);
  float inv = 1.f / fmaxf(sqrtf(s), 1e-12f);
  vf4* d4 = (vf4*)dst;
  d4[lane] = A*inv;
  if (lane<11) d4[64+lane] = Bv*inv;
}

// ---- K2: grid 24576 = 16384 compute + 8192 fill, INTERLEAVED (b%3==2 ->
// fill row b/3): store-bound fill overlaps latency-bound compute on every CU.
// (R7 showed spreading fill into the small kernels regresses — keep it here.)
__global__ __launch_bounds__(256) void k_prime(const float* __restrict__ su,
    const float* __restrict__ sv, const int* __restrict__ ub,
    const int* __restrict__ vb, const int* __restrict__ uoff,
    const int* __restrict__ voff, float* __restrict__ spr,
    float* __restrict__ svp, float* __restrict__ e1u, float* __restrict__ e1v,
    const float* __restrict__ h1, float* __restrict__ mapbase, int Nu, int Nv){
  int b = blockIdx.x;
  int tid = threadIdx.x, lane = tid & 63, w = tid >> 6;
  int r = b % 3;
  if (r == 2){ fill_row(b/3, ub, voff, mapbase, Nv, tid); return; }
  int idx = (b/3)*2 + r;                   // [0, 16384)
  bool isU = (idx < Nu);
  int i = isU ? idx : idx - Nu;
  const float* xa = isU ? su : sv;
  const float* xb = isU ? sv : su;
  const int* mybatch = isU ? ub : vb;
  const int* ooff    = isU ? voff : uoff;
  float* prime = isU ? spr : svp;
  float* eout  = isU ? e1u : e1v;

  __shared__ __align__(16) float xrow[304];
  __shared__ __align__(16) float prl[4*304];
  __shared__ float qv[2*HDIM];
  __shared__ float red[4];
  const float* rowp = xa + (size_t)i*HDIM;
  for (int t=tid; t<HDIM;   t+=256) xrow[t] = rowp[t];
  for (int t=tid; t<2*HDIM; t+=256) qv[t]   = h1[t];
  int g = mybatch[i];
  int js = ooff[g], je = ooff[g+1];
  __syncthreads();

  const vf4* x4 = (const vf4*)xrow;
  vf4 xA = x4[lane];
  vf4 xB = (lane<11)? x4[64+lane] : (vf4){0.f,0.f,0.f,0.f};
  vf4 prA = {0.f,0.f,0.f,0.f}, prB = {0.f,0.f,0.f,0.f};
  for (int j = js + w; j < je; j += 4){
    const vf4* orow = (const vf4*)(xb + (size_t)j*HDIM);
    vf4 oA = orow[lane];
    vf4 oB = (lane<11)? orow[64+lane] : (vf4){0.f,0.f,0.f,0.f};
    float d = oA.x*xA.x + oA.y*xA.y + oA.z*xA.z + oA.w*xA.w
            + oB.x*xB.x + oB.y*xB.y + oB.z*xB.z + oB.w*xB.w;
    d = wred_sum(d);
    if (isU && lane==0) mapbase[(size_t)i*Nv + j] = d;
    prA += d * oA;
    prB += d * oB;
  }
  vf4* p4 = (vf4*)(prl + w*304);
  p4[lane] = prA;
  if (lane<11) p4[64+lane] = prB;
  __syncthreads();
  float ep = 0.f;
  for (int t=tid; t<HDIM; t+=256){
    float s = prl[t] + prl[304+t] + prl[608+t] + prl[912+t];
    prime[(size_t)i*HDIM + t] = s;
    ep += xrow[t]*qv[t] + s*qv[HDIM+t];
  }
  ep = wred_sum(ep);
  if (lane==0) red[w] = ep;
  __syncthreads();
  if (tid==0) eout[i] = red[0]+red[1]+red[2]+red[3];
}

// ---- K3: 512 blocks: segment softmax over e1 + r1 -------------------------
__global__ __launch_bounds__(256) void k_r1(const float* __restrict__ su,
    const float* __restrict__ sv, const float* __restrict__ spr,
    const float* __restrict__ svp, const float* __restrict__ e1u,
    const float* __restrict__ e1v, const int* __restrict__ uoff,
    const int* __restrict__ voff, float* __restrict__ r1){
  int tid = threadIdx.x, lane = tid & 63, w = tid >> 6;
  int bs = blockIdx.x; int set = bs >> 8; int g = bs & 255;
  const float* x  = set? sv  : su;
  const float* pr = set? svp : spr;
  const float* e  = set? e1v : e1u;
  const int* off  = set? voff: uoff;
  __shared__ float al[2048]; __shared__ float red[4]; __shared__ float shv;
  int ns = off[g], ne = off[g+1]; int n = ne - ns;
  float m = -INFINITY;
  for (int t=ns+tid; t<ne; t+=256) m = fmaxf(m, e[t]);
  m = wred_max(m);
  if (lane==0) red[w]=m;
  __syncthreads();
  if (tid==0) shv = fmaxf(fmaxf(red[0],red[1]),fmaxf(red[2],red[3]));
  __syncthreads();
  float emax = shv;
  float s = 0.f;
  for (int t=tid; t<n; t+=256){ float a = expf(e[ns+t]-emax); if (t<2048) al[t]=a; s += a; }
  s = wred_sum(s);
  __syncthreads();
  if (lane==0) red[w]=s;
  __syncthreads();
  if (tid==0) shv = red[0]+red[1]+red[2]+red[3];
  __syncthreads();
  float inv = 1.f/(shv + 1e-16f);
  float acc[3] = {0.f,0.f,0.f};
  #pragma unroll 4
  for (int nn=0; nn<n; nn++){
    float a = (nn<2048)? al[nn] : expf(e[ns+nn]-emax);
    const float* xr = x  + (size_t)(ns+nn)*HDIM;
    const float* pp = pr + (size_t)(ns+nn)*HDIM;
    #pragma unroll
    for(int u=0;u<3;u++){ int c = tid + u*256; if (c<DDIM){
        float xv = (c<HDIM)? xr[c] : pp[c-HDIM]; acc[u] += a*xv; } }
  }
  #pragma unroll
  for(int u=0;u<3;u++){ int c = tid + u*256; if (c<DDIM) r1[(size_t)bs*DDIM + c] = acc[u]*inv; }
}

// ---- K4: fused GEMM (gates = r1 @ Wih[:,600:].T) + step-2 LSTM pointwise.
// 32 gs x 64 col tile (cols = 4 gates x 16 d), grid 38x16 = 608 blocks. -----
__global__ __launch_bounds__(256) void k_gemm_lstm(const float* __restrict__ r1,
    const float* __restrict__ Wih, const float* __restrict__ gbase,
    const float* __restrict__ c1, float* __restrict__ h2){
  __shared__ __align__(16) float smem[32*68];   // gates phase; K phase aliases
  float* Al = smem;            // 16*36
  float* Bl = smem + 16*36;    // 16*68
  int tid = threadIdx.x;
  int d0  = blockIdx.x*16;     // 38 blocks: d0 = 0..592 (last has 8 valid)
  int gs0 = blockIdx.y*32;
  int tx = tid & 15, ty = tid >> 4;
  float acc[2][4] = {};
  for (int kt=0; kt<600; kt+=16){
    int k = kt + tx;
    bool kok = (k < 600);
    #pragma unroll
    for (int u=0; u<2; u++){
      int rl = ty + u*16;
      Al[tx*36 + rl] = kok ? r1[(size_t)(gs0+rl)*DDIM + k] : 0.f;
    }
    #pragma unroll
    for (int u=0; u<4; u++){
      int cl = ty + u*16;                 // 0..63
      int gate = cl >> 4, dd = cl & 15;
      int d = d0 + dd;
      Bl[tx*68 + cl] = (kok && d < 600)
          ? Wih[(size_t)(gate*600 + d)*1200 + 600 + k] : 0.f;
    }
    __syncthreads();
    #pragma unroll
    for (int kk=0; kk<16; kk++){
      vf2 av = ((const vf2*)(Al + kk*36))[ty];
      vf4 bv = ((const vf4*)(Bl + kk*68))[tx];
      float a[2]={av.x,av.y}, bb[4]={bv.x,bv.y,bv.z,bv.w};
      #pragma unroll
      for(int mm=0;mm<2;mm++)
        #pragma unroll
        for(int nn=0;nn<4;nn++) acc[mm][nn] += a[mm]*bb[nn];
    }
    __syncthreads();
  }
  #pragma unroll
  for (int mm=0; mm<2; mm++){
    vf4 o = {acc[mm][0], acc[mm][1], acc[mm][2], acc[mm][3]};
    ((vf4*)(smem + (ty*2+mm)*68))[tx] = o;
  }
  __syncthreads();
  int d_l = tid & 15, r0 = tid >> 4;
  int d = d0 + d_l;
  if (d < 600){
    float gb_i = gbase[d], gb_f = gbase[600+d], gb_g = gbase[1200+d], gb_o = gbase[1800+d];
    float cc1 = c1[d];
    #pragma unroll
    for (int u=0; u<2; u++){
      int rl = r0 + u*16;
      const float* gr = smem + rl*68;
      float gi = gr[d_l]      + gb_i;
      float gf = gr[16+d_l]   + gb_f;
      float gG = gr[32+d_l]   + gb_g;
      float go = gr[48+d_l]   + gb_o;
      float c  = sigm(gf)*cc1 + sigm(gi)*tanhf(gG);
      h2[(size_t)(gs0+rl)*DDIM + d] = sigm(go)*tanhf(c);
    }
  }
}

// ---- K5: 512 blocks: e2 (in LDS) -> segment softmax -> r2 -> atomicAdd pred
__global__ __launch_bounds__(256) void k_r2(const float* __restrict__ su,
    const float* __restrict__ sv, const float* __restrict__ spr,
    const float* __restrict__ svp, const int* __restrict__ uoff,
    const int* __restrict__ voff, const float* __restrict__ h2,
    const float* __restrict__ pW, float* __restrict__ e2u,
    float* __restrict__ e2v, float* __restrict__ outp){
  int tid = threadIdx.x, lane = tid & 63, w = tid >> 6;
  int bs = blockIdx.x; int set = bs >> 8; int g = bs & 255;
  const float* x  = set? sv  : su;
  const float* pr = set? svp : spr;
  const int* off  = set? voff: uoff;
  float* e2g      = set? e2v : e2u;        // overflow fallback only
  __shared__ float q[DDIM]; __shared__ float e2l[128]; __shared__ float al[128];
  __shared__ float red[4]; __shared__ float shv;
  for (int t=tid; t<DDIM; t+=256) q[t] = h2[(size_t)bs*DDIM + t];
  int ns = off[g], ne = off[g+1]; int n = ne - ns;
  __syncthreads();
  #pragma unroll 2
  for (int node = ns + w; node < ne; node += 4){
    const float* xr = x  + (size_t)node*HDIM;
    const float* pp = pr + (size_t)node*HDIM;
    float d = 0.f;
    #pragma unroll
    for(int c=0;c<10;c++){ int k = lane + 64*c; if (k<DDIM){
        float xv = (k<HDIM)? xr[k] : pp[k-HDIM]; d += xv*q[k]; } }
    d = wred_sum(d);
    if (lane==0){ int t = node-ns; if (t<128) e2l[t] = d; else e2g[node] = d; }
  }
  __syncthreads();
  float m = -INFINITY;
  for (int t=tid; t<n; t+=256) m = fmaxf(m, (t<128)? e2l[t] : e2g[ns+t]);
  m = wred_max(m);
  if (lane==0) red[w]=m;
  __syncthreads();
  if (tid==0) shv = fmaxf(fmaxf(red[0],red[1]),fmaxf(red[2],red[3]));
  __syncthreads();
  float emax = shv;
  float s = 0.f;
  for (int t=tid; t<n; t+=256){
    float a = expf(((t<128)? e2l[t] : e2g[ns+t]) - emax);
    if (t<128) al[t]=a; else e2g[ns+t]=a;
    s += a;
  }
  s = wred_sum(s);
  __syncthreads();
  if (lane==0) red[w]=s;
  __syncthreads();
  if (tid==0) shv = red[0]+red[1]+red[2]+red[3];
  __syncthreads();
  float inv = 1.f/(shv + 1e-16f);
  float acc[3] = {0.f,0.f,0.f};
  #pragma unroll 4
  for (int nn=0; nn<n; nn++){
    float a = (nn<128)? al[nn] : e2g[ns+nn];
    const float* xr = x  + (size_t)(ns+nn)*HDIM;
    const float* pp = pr + (size_t)(ns+nn)*HDIM;
    #pragma unroll
    for(int u=0;u<3;u++){ int c = tid + u*256; if (c<DDIM){
        float xv = (c<HDIM)? xr[c] : pp[c-HDIM]; acc[u] += a*xv; } }
  }
  int hoff = set? 1200 : 0;
  float p = 0.f;
  #pragma unroll
  for(int u=0;u<3;u++){ int c = tid + u*256; if (c<DDIM) p += (acc[u]*inv)*pW[hoff+600+c]; }
  for (int t=tid; t<DDIM; t+=256) p += q[t]*pW[hoff+t];
  p = wred_sum(p);
  __syncthreads();
  if (lane==0) red[w] = p;
  __syncthreads();
  if (tid==0) atomicAdd(&outp[g], red[0]+red[1]+red[2]+red[3]);
}

extern "C" void kernel_launch(void* const* d_in, const int* in_sizes, int n_in,
                              void* d_out, int out_size, void* d_ws, size_t ws_size,
                              hipStream_t stream) {
  const float* solute_x  = (const float*)d_in[0];
  const float* solvent_x = (const float*)d_in[1];
  const int*   ub        = (const int*)d_in[2];
  const int*   vb        = (const int*)d_in[3];
  const float* Wih  = (const float*)d_in[5];
  const float* Whh  = (const float*)d_in[6];
  const float* b_ih = (const float*)d_in[7];
  const float* b_hh = (const float*)d_in[8];
  const float* pW   = (const float*)d_in[9];
  const float* pb   = (const float*)d_in[10];

  int Nu = in_sizes[0] / HDIM;
  int Nv = in_sizes[1] / HDIM;

  float* out = (float*)d_out;
  int predn = out_size - Nu*Nv;        // = 256
  float* mapbase = out + predn;

  float* ws = (float*)d_ws;
  float* su    = ws;
  float* sv    = su    + (size_t)Nu*HDIM;
  float* spr   = sv    + (size_t)Nv*HDIM;
  float* svp   = spr   + (size_t)Nu*HDIM;
  float* e1u   = svp   + (size_t)Nv*HDIM;  // Nu
  float* e1v   = e1u   + Nu;               // Nv
  float* h1    = e1v   + Nv;               // 600
  float* c1    = h1    + DDIM;             // 600
  float* r1    = c1    + DDIM;             // 512*600
  float* gbase = r1    + 512*DDIM;         // 2400
  float* h2    = gbase + 2400;             // 512*600
  int*   uoff  = (int*)(h2 + 512*DDIM);    // 257
  int*   voff  = uoff + 257;               // 257

  k_norm_off<<<dim3((Nu+Nv)/4 + 1 + 600), dim3(256), 0, stream>>>(
      solute_x, solvent_x, su, sv, Nu, Nv, ub, vb, uoff, voff,
      b_ih, b_hh, h1, c1, pb, out, Wih, Whh, gbase);
  k_prime<<<dim3(24576), dim3(256), 0, stream>>>(
      su, sv, ub, vb, uoff, voff, spr, svp, e1u, e1v, h1, mapbase, Nu, Nv);
  k_r1<<<dim3(512), dim3(256), 0, stream>>>(
      su, sv, spr, svp, e1u, e1v, uoff, voff, r1);
  k_gemm_lstm<<<dim3(38, 16), dim3(256), 0, stream>>>(r1, Wih, gbase, c1, h2);
  k_r2<<<dim3(512), dim3(256), 0, stream>>>(
      su, sv, spr, svp, uoff, voff, h2, pW, e1u, e1v, out);
}